// Round 8
// baseline (451.117 us; speedup 1.0000x reference)
//
#include <hip/hip_runtime.h>
#include <stdint.h>

#define T_SEQ 2048
#define NH 16
#define HD 128
#define CC 2048
#define N3 6144
#define MM 4096   // B*T

typedef short bf16x8 __attribute__((ext_vector_type(8)));
typedef float f32x4 __attribute__((ext_vector_type(4)));

__device__ __forceinline__ unsigned short f2bf(float f) {
  unsigned int u = __float_as_uint(f);
  u += 0x7FFF + ((u >> 16) & 1);   // RNE
  return (unsigned short)(u >> 16);
}
__device__ __forceinline__ float bf2f(unsigned short h) {
  return __uint_as_float(((unsigned int)h) << 16);
}

// ---------------- transpose + fp32->bf16 convert: out[n][k] = in[k][n] ----------------
__global__ __launch_bounds__(256) void k_transpose_cvt(const float* __restrict__ in,
                                                       unsigned short* __restrict__ out,
                                                       int K, int N) {
  __shared__ float tile[32][33];
  int k0 = blockIdx.x * 32;
  int n0 = blockIdx.y * 32;
  int tx = threadIdx.x & 31, ty = threadIdx.x >> 5;   // ty 0..7
  #pragma unroll
  for (int r = ty; r < 32; r += 8)
    tile[r][tx] = in[(size_t)(k0 + r) * N + n0 + tx];
  __syncthreads();
  #pragma unroll
  for (int r = ty; r < 32; r += 8)
    out[(size_t)(n0 + r) * K + k0 + tx] = f2bf(tile[tx][r]);
}

// ---------------- fp32 -> bf16 elementwise (x) ----------------
__global__ __launch_bounds__(256) void k_cvt(const float* __restrict__ in,
                                             unsigned short* __restrict__ out, int n4) {
  int i = blockIdx.x * 256 + threadIdx.x;
  if (i >= n4) return;
  float4 v = ((const float4*)in)[i];
  ushort4 o;
  o.x = f2bf(v.x); o.y = f2bf(v.y); o.z = f2bf(v.z); o.w = f2bf(v.w);
  ((ushort4*)out)[i] = o;
}

// ---------------- bf16 GEMM, 8-phase template, BM=128, BN=NJ*64 (round-5 config) --------
// 512 threads = 8 waves (2M x 4N). BK=64, 2 K-tiles/iteration.
// LDS per dbuf: A unit (128x64 bf16 = 16KB) + BU=NJ/2 B units. NJ=6: 128KB, NJ=4: 96KB.
// Swizzle: involutive XOR of byte bits[4:6] with row bits[0:2] (rows = 128B).
// Stage plan (1 unit/phase): ph1: b.A->d1, ph2..: a'.B->d0, ph5: a'.A->d0, ph6..: b'.B->d1.
// vmcnt(6) (NJ=6) / vmcnt(4) (NJ=4) at ph4 & ph8 only.
// EPI==0: fp32 C.  EPI==1: scatter bf16 into q/k/v (B,H,T,D).  MMAJ: XCD-chunk axis.
template<int NJ, int EPI, int MMAJ>
__global__ __launch_bounds__(512, 1) void k_gemm8(const unsigned short* __restrict__ A,
                                                  const unsigned short* __restrict__ Bt,
                                                  float* __restrict__ C,
                                                  unsigned short* __restrict__ qo,
                                                  unsigned short* __restrict__ ko,
                                                  unsigned short* __restrict__ vo,
                                                  int M, int N, int K) {
  constexpr int BU = NJ / 2;             // B units of 128 rows
  constexpr int DSTRIDE = (1 + BU) * 16384;
  extern __shared__ __align__(16) char lds[];
  const int tid = threadIdx.x;
  const int lane = tid & 63;
  const int lr = lane & 15, lg = lane >> 4;
  const int wave = tid >> 6;
  const int wm = wave >> 2, wn = wave & 3;
  // T1 bijective XCD swizzle (nwg % 8 == 0 here)
  const int nwg = gridDim.x;
  const int bid = blockIdx.x;
  const int wg = (bid & 7) * (nwg >> 3) + (bid >> 3);
  const int GX = M >> 7;
  const int GN = N / (NJ * 64);
  const int mt = MMAJ ? (wg % GX) : (wg / GN);
  const int nt = MMAJ ? (wg / GX) : (wg % GN);
  const int m0 = mt * 128, n0 = nt * NJ * 64;
  const int NT = K >> 6;

  // stage one 128x64 unit of tile t: op==0 -> A, op==1 -> B unit h
  auto STAGE = [&](int d, int op, int h, int t) {
    const unsigned short* src = op ? Bt : A;
    const int r0 = (op ? n0 + h * 128 : m0);
    const int kc = t * 64;
    char* base = lds + d * DSTRIDE + op * 16384 + h * 16384;
    #pragma unroll
    for (int l = 0; l < 2; ++l) {
      int p = (l * 512 + tid) * 16;
      int qq = p ^ (((p >> 7) & 7) << 4);
      const unsigned short* g = src + (size_t)(r0 + (qq >> 7)) * K + kc + ((qq & 127) >> 1);
      __builtin_amdgcn_global_load_lds(
          (const __attribute__((address_space(1))) void*)g,
          (__attribute__((address_space(3))) void*)(base + (l * 512 + (tid & 448)) * 16),
          16, 0, 0);
    }
  };
  // swizzled fragment read; row spans the whole region (A: 128 rows, B: BU*128 rows)
  auto RD = [&](int d, int op, int row, int kb) -> bf16x8 {
    const char* base = lds + d * DSTRIDE + op * 16384;
    int p = row * 128 + kb;
    p ^= ((p >> 7) & 7) << 4;
    return *(const bf16x8*)(base + p);
  };

  f32x4 acc[4][NJ];
  #pragma unroll
  for (int i = 0; i < 4; ++i)
    #pragma unroll
    for (int j = 0; j < NJ; ++j) acc[i][j] = (f32x4){0.f, 0.f, 0.f, 0.f};

  bf16x8 bfrg[NJ][2];

#define PHASE(D, MI, READB, DOST, SD, SO, SH, ST, VM)                                    \
  {                                                                                      \
    if (READB) {                                                                         \
      _Pragma("unroll")                                                                  \
      for (int nj = 0; nj < NJ; ++nj)                                                    \
        _Pragma("unroll")                                                                \
        for (int ks = 0; ks < 2; ++ks)                                                   \
          bfrg[nj][ks] = RD(D, 1, wn * NJ * 16 + nj * 16 + lr, ks * 64 + lg * 16);       \
    }                                                                                    \
    bf16x8 af[2];                                                                        \
    _Pragma("unroll")                                                                    \
    for (int ks = 0; ks < 2; ++ks)                                                       \
      af[ks] = RD(D, 0, wm * 64 + (MI) * 16 + lr, ks * 64 + lg * 16);                    \
    if (DOST) STAGE(SD, SO, SH, ST);                                                     \
    __builtin_amdgcn_s_barrier();                                                        \
    asm volatile("s_waitcnt lgkmcnt(0)" ::: "memory");                                   \
    __builtin_amdgcn_s_setprio(1);                                                       \
    _Pragma("unroll")                                                                    \
    for (int nj = 0; nj < NJ; ++nj)                                                      \
      _Pragma("unroll")                                                                  \
      for (int ks = 0; ks < 2; ++ks)                                                     \
        acc[MI][nj] = __builtin_amdgcn_mfma_f32_16x16x32_bf16(af[ks], bfrg[nj][ks], acc[MI][nj], 0, 0, 0); \
    __builtin_amdgcn_s_setprio(0);                                                       \
    if ((VM) == 6) asm volatile("s_waitcnt vmcnt(6)" ::: "memory");                      \
    if ((VM) == 4) asm volatile("s_waitcnt vmcnt(4)" ::: "memory");                      \
    __builtin_amdgcn_s_barrier();                                                        \
  }

  // prologue: tile0 full -> d0 (B units then A), tile1 B units -> d1 (t1.A staged in ph1)
  const int t1 = NT > 1 ? 1 : 0;
  #pragma unroll
  for (int h = 0; h < BU; ++h) STAGE(0, 1, h, 0);
  STAGE(0, 0, 0, 0);
  #pragma unroll
  for (int h = 0; h < BU; ++h) STAGE(1, 1, h, t1);
  if (NJ == 6) asm volatile("s_waitcnt vmcnt(6)" ::: "memory");
  else         asm volatile("s_waitcnt vmcnt(4)" ::: "memory");
  __builtin_amdgcn_s_barrier();

  for (int it = 0; it < (NT >> 1); ++it) {
    const int tb  = 2 * it + 1;
    const int ta1 = min(2 * it + 2, NT - 1);
    const int tb1 = min(2 * it + 3, NT - 1);
    if (NJ == 6) {
      // K-tile a (d0)
      PHASE(0, 0, true,  true, 1, 0, 0, tb,  -1)   // stage b.A  -> d1
      PHASE(0, 1, false, true, 0, 1, 0, ta1, -1)   // stage a'.B0 -> d0
      PHASE(0, 2, false, true, 0, 1, 1, ta1, -1)   // stage a'.B1 -> d0
      PHASE(0, 3, false, true, 0, 1, 2, ta1,  6)   // stage a'.B2 -> d0; vmcnt(6)
      // K-tile b (d1)
      PHASE(1, 0, true,  true, 0, 0, 0, ta1, -1)   // stage a'.A -> d0
      PHASE(1, 1, false, true, 1, 1, 0, tb1, -1)   // stage b'.B0 -> d1
      PHASE(1, 2, false, true, 1, 1, 1, tb1, -1)   // stage b'.B1 -> d1
      PHASE(1, 3, false, true, 1, 1, 2, tb1,  6)   // stage b'.B2 -> d1; vmcnt(6)
    } else {
      PHASE(0, 0, true,  true,  1, 0, 0, tb,  -1)  // stage b.A  -> d1
      PHASE(0, 1, false, true,  0, 1, 0, ta1, -1)  // stage a'.B0 -> d0
      PHASE(0, 2, false, true,  0, 1, 1, ta1, -1)  // stage a'.B1 -> d0
      PHASE(0, 3, false, false, 0, 0, 0, 0,    4)  // vmcnt(4)
      PHASE(1, 0, true,  true,  0, 0, 0, ta1, -1)  // stage a'.A -> d0
      PHASE(1, 1, false, true,  1, 1, 0, tb1, -1)  // stage b'.B0 -> d1
      PHASE(1, 2, false, true,  1, 1, 1, tb1, -1)  // stage b'.B1 -> d1
      PHASE(1, 3, false, false, 0, 0, 0, 0,    4)  // vmcnt(4)
    }
  }
#undef PHASE

  // epilogue
  #pragma unroll
  for (int mi = 0; mi < 4; ++mi) {
    #pragma unroll
    for (int nj = 0; nj < NJ; ++nj) {
      #pragma unroll
      for (int j = 0; j < 4; ++j) {
        int m = m0 + wm * 64 + mi * 16 + lg * 4 + j;
        int n = n0 + wn * NJ * 16 + nj * 16 + lr;
        float val = acc[mi][nj][j];
        if (EPI == 0) {
          C[(size_t)m * N + n] = val;
        } else {
          int which = n >> 11, cc = n & 2047;
          int h = cc >> 7, d = cc & 127;
          int b = m >> 11, t = m & 2047;
          unsigned short* dst = which == 0 ? qo : (which == 1 ? ko : vo);
          dst[(((size_t)(b * NH + h)) * T_SEQ + t) * HD + d] = f2bf(val);
        }
      }
    }
  }
}

// ---------------- RoPE in place on q (scaled by 1/sqrt(D)) and k ----------------
__global__ __launch_bounds__(256) void k_rope(unsigned short* __restrict__ q,
                                              unsigned short* __restrict__ k) {
  int i = blockIdx.x * 256 + threadIdx.x;   // over 32 * 2048 * 64
  int d = i & 63;
  int t = (i >> 6) & (T_SEQ - 1);
  int bh = i >> 17;
  float invf = exp2f((float)(-2 * d) * (13.287712379549449f / 128.f)); // 10000^(-2d/128)
  float ang = (float)t * invf;
  float c = cosf(ang), s = sinf(ang);
  size_t base = ((size_t)bh * T_SEQ + t) * HD + d;
  const float scale = 0.08838834764831845f;  // 1/sqrt(128)
  float q1 = bf2f(q[base]), q2 = bf2f(q[base + 64]);
  q[base]      = f2bf((q1 * c - q2 * s) * scale);
  q[base + 64] = f2bf((q2 * c + q1 * s) * scale);
  float k1 = bf2f(k[base]), k2 = bf2f(k[base + 64]);
  k[base]      = f2bf(k1 * c - k2 * s);
  k[base + 64] = f2bf(k2 * c + k1 * s);
}

// ---------------- bf16 transpose per (b,h): (T,D) -> (D,T) ----------------
__global__ __launch_bounds__(256) void k_transpose_v(const unsigned short* __restrict__ in,
                                                     unsigned short* __restrict__ out) {
  __shared__ unsigned short tile[32][33];
  int bh = blockIdx.z;
  int t0 = blockIdx.x * 32, d0 = blockIdx.y * 32;
  int tx = threadIdx.x & 31, ty = threadIdx.x >> 5;
  const unsigned short* src = in + (size_t)bh * T_SEQ * HD;
  unsigned short* dst = out + (size_t)bh * HD * T_SEQ;
  #pragma unroll
  for (int r = ty; r < 32; r += 8)
    tile[r][tx] = src[(size_t)(t0 + r) * HD + d0 + tx];
  __syncthreads();
  #pragma unroll
  for (int r = ty; r < 32; r += 8)
    dst[(size_t)(d0 + r) * T_SEQ + t0 + tx] = tile[tx][r];
}

// ---------------- causal flash attention: barrier-free, K/V frags direct global->VGPR ----
// Q,K: (B*H, T, D) bf16 (q pre-scaled).  Vt: (B*H, D, T) bf16.  Y: (B, T, C) bf16.
// Per 64-col KV tile: each wave loads its MFMA K/V fragments straight from global (L2/L3-
// resident; 16-lane x 64B row segments). LDS holds only the per-wave P strip -> no
// __syncthreads anywhere. V-frag loads are issued before softmax so L2 latency hides (T14).
__global__ __launch_bounds__(256, 2) void k_attn(const unsigned short* __restrict__ Q,
                                                 const unsigned short* __restrict__ K,
                                                 const unsigned short* __restrict__ Vt,
                                                 unsigned short* __restrict__ Y) {
  __shared__ __align__(16) unsigned short Ps[64 * 80];    // per-wave 16-row strips, 160B rows
  const int bh = blockIdx.x;                    // fast dim: heads spread over XCDs
  const int qt = (T_SEQ / 64 - 1) - blockIdx.y; // heavy Q-tiles dispatch first (LPT)
  const int b = bh >> 4, h = bh & 15;
  const int tid = threadIdx.x, wave = tid >> 6, lane = tid & 63;
  const int lr = lane & 15, lg = lane >> 4;
  const int q0 = qt * 64;
  const unsigned short* Qb = Q + (size_t)bh * T_SEQ * HD;
  const unsigned short* Kb = K + (size_t)bh * T_SEQ * HD;
  const unsigned short* Vb = Vt + (size_t)bh * HD * T_SEQ;

  // hoist Q fragments: wave's 16 rows, 4 K-slices of 32
  bf16x8 qf[4];
  #pragma unroll
  for (int kk = 0; kk < 4; ++kk)
    qf[kk] = *(const bf16x8*)(Qb + (size_t)(q0 + wave * 16 + lr) * HD + kk * 32 + lg * 8);

  const f32x4 fzero = {0.f, 0.f, 0.f, 0.f};
  f32x4 oacc[8];
  #pragma unroll
  for (int nd = 0; nd < 8; ++nd) oacc[nd] = fzero;
  float mrow[4], lrow[4];
  #pragma unroll
  for (int j = 0; j < 4; ++j) { mrow[j] = -1e30f; lrow[j] = 0.f; }

  for (int jt = 0; jt <= qt; ++jt) {
    const int tk0 = jt * 64;

    // K fragments direct from global (B-operand pattern: row = nr*16+lr, bytes kk*64+lg*16)
    bf16x8 kf[4][4];
    #pragma unroll
    for (int nr = 0; nr < 4; ++nr)
      #pragma unroll
      for (int kk = 0; kk < 4; ++kk)
        kf[nr][kk] = *(const bf16x8*)(Kb + (size_t)(tk0 + nr * 16 + lr) * HD + kk * 32 + lg * 8);

    // S = Q K^T
    f32x4 sacc[4];
    #pragma unroll
    for (int nr = 0; nr < 4; ++nr) sacc[nr] = fzero;
    __builtin_amdgcn_s_setprio(1);
    #pragma unroll
    for (int nr = 0; nr < 4; ++nr)
      #pragma unroll
      for (int kk = 0; kk < 4; ++kk)
        sacc[nr] = __builtin_amdgcn_mfma_f32_16x16x32_bf16(qf[kk], kf[nr][kk], sacc[nr], 0, 0, 0);
    __builtin_amdgcn_s_setprio(0);

    // V fragments issued now; latency hides under softmax (T14)
    bf16x8 vf[8][2];
    #pragma unroll
    for (int nd = 0; nd < 8; ++nd)
      #pragma unroll
      for (int kk = 0; kk < 2; ++kk)
        vf[nd][kk] = *(const bf16x8*)(Vb + (size_t)(nd * 16 + lr) * T_SEQ + tk0 + kk * 32 + lg * 8);

    if (jt == qt) {  // causal mask on diagonal tile
      #pragma unroll
      for (int nr = 0; nr < 4; ++nr)
        #pragma unroll
        for (int j = 0; j < 4; ++j) {
          int qg = q0 + wave * 16 + lg * 4 + j;
          int cg = tk0 + nr * 16 + lr;
          if (cg > qg) sacc[nr][j] = -1e30f;
        }
    }

    // online softmax (rows distributed: row = lg*4+j, 16 lanes share a row)
    float oscale[4];
    #pragma unroll
    for (int j = 0; j < 4; ++j) {
      float tmax = fmaxf(fmaxf(sacc[0][j], sacc[1][j]), fmaxf(sacc[2][j], sacc[3][j]));
      #pragma unroll
      for (int m = 1; m <= 8; m <<= 1) tmax = fmaxf(tmax, __shfl_xor(tmax, m));
      float mnew = fmaxf(mrow[j], tmax);
      oscale[j] = __expf(mrow[j] - mnew);
      float rsum = 0.f;
      #pragma unroll
      for (int nr = 0; nr < 4; ++nr) {
        float p = __expf(sacc[nr][j] - mnew);
        Ps[(wave * 16 + lg * 4 + j) * 80 + nr * 16 + lr] = f2bf(p);
        rsum += p;
      }
      #pragma unroll
      for (int m = 1; m <= 8; m <<= 1) rsum += __shfl_xor(rsum, m);
      lrow[j] = lrow[j] * oscale[j] + rsum;
      mrow[j] = mnew;
    }
    #pragma unroll
    for (int nd = 0; nd < 8; ++nd)
      #pragma unroll
      for (int j = 0; j < 4; ++j) oacc[nd][j] *= oscale[j];

    // PV: O += P * V  (P strip is wave-local; DS ops are in-order per wave, no barrier)
    bf16x8 pf[2];
    #pragma unroll
    for (int kk = 0; kk < 2; ++kk)
      pf[kk] = *(const bf16x8*)(Ps + (wave * 16 + lr) * 80 + kk * 32 + lg * 8);
    __builtin_amdgcn_s_setprio(1);
    #pragma unroll
    for (int nd = 0; nd < 8; ++nd)
      #pragma unroll
      for (int kk = 0; kk < 2; ++kk)
        oacc[nd] = __builtin_amdgcn_mfma_f32_16x16x32_bf16(pf[kk], vf[nd][kk], oacc[nd], 0, 0, 0);
    __builtin_amdgcn_s_setprio(0);
  }

  // epilogue: O / l -> Y (B,T,C)
  #pragma unroll
  for (int j = 0; j < 4; ++j) {
    float inv = 1.f / lrow[j];
    int qg = q0 + wave * 16 + lg * 4 + j;
    size_t base = ((size_t)b * T_SEQ + qg) * CC + h * HD;
    #pragma unroll
    for (int nd = 0; nd < 8; ++nd)
      Y[base + nd * 16 + lr] = f2bf(oacc[nd][j] * inv);
  }
}

extern "C" void kernel_launch(void* const* d_in, const int* in_sizes, int n_in,
                              void* d_out, int out_size, void* d_ws, size_t ws_size,
                              hipStream_t stream) {
  const float* x     = (const float*)d_in[0];
  const float* Wqkv  = (const float*)d_in[1];
  const float* Wproj = (const float*)d_in[2];
  float* out = (float*)d_out;
  char* ws = (char*)d_ws;
  const size_t MB = 1024 * 1024;
  unsigned short* WqkvT  = (unsigned short*)(ws + 0);        // 24MB; dead after GEMM1
  unsigned short* vt     = (unsigned short*)(ws + 0);        // 16MB, aliases WqkvT
  unsigned short* WprojT = (unsigned short*)(ws + 24 * MB);  // 8MB
  unsigned short* xb     = (unsigned short*)(ws + 32 * MB);  // 16MB; dead after GEMM1
  unsigned short* y      = xb;                               // aliases xb
  unsigned short* q      = (unsigned short*)(ws + 48 * MB);  // 16MB
  unsigned short* k      = (unsigned short*)(ws + 64 * MB);  // 16MB
  unsigned short* v      = (unsigned short*)(ws + 80 * MB);  // 16MB  (total 96MB)

  k_transpose_cvt<<<dim3(CC / 32, N3 / 32), 256, 0, stream>>>(Wqkv, WqkvT, CC, N3);
  k_transpose_cvt<<<dim3(CC / 32, CC / 32), 256, 0, stream>>>(Wproj, WprojT, CC, CC);
  k_cvt<<<(MM * CC / 4) / 256, 256, 0, stream>>>(x, xb, MM * CC / 4);
  // GEMM1: 4096 x 6144 x 2048, BM=128 BN=384 -> grid 512 (exactly 2 gens), m-major chunks
  k_gemm8<6, 1, 1><<<dim3((MM / 128) * (N3 / 384)), 512, 131072, stream>>>(
      xb, WqkvT, nullptr, q, k, v, MM, N3, CC);
  k_rope<<<(32 * T_SEQ * 64) / 256, 256, 0, stream>>>(q, k);
  k_transpose_v<<<dim3(T_SEQ / 32, HD / 32, 32), 256, 0, stream>>>(v, vt);
  k_attn<<<dim3(32, T_SEQ / 64), 256, 0, stream>>>(q, k, vt, y);
  // GEMM2: 4096 x 2048 x 2048, BM=128 BN=256 -> grid 256 (exactly 1/CU), n-major chunks
  k_gemm8<4, 0, 0><<<dim3((MM / 128) * (CC / 256)), 512, 98304, stream>>>(
      y, WprojT, out, nullptr, nullptr, nullptr, MM, CC, CC);
}

// Round 9
// 304.042 us; speedup vs baseline: 1.4837x; 1.4837x over previous
//
#include <hip/hip_runtime.h>
#include <stdint.h>

#define T_SEQ 2048
#define NH 16
#define HD 128
#define CC 2048
#define N3 6144
#define MM 4096   // B*T

typedef short bf16x8 __attribute__((ext_vector_type(8)));
typedef float f32x4 __attribute__((ext_vector_type(4)));

__device__ __forceinline__ unsigned short f2bf(float f) {
  unsigned int u = __float_as_uint(f);
  u += 0x7FFF + ((u >> 16) & 1);   // RNE
  return (unsigned short)(u >> 16);
}
__device__ __forceinline__ float bf2f(unsigned short h) {
  return __uint_as_float(((unsigned int)h) << 16);
}

// ---------------- transpose + fp32->bf16 convert: out[n][k] = in[k][n] ----------------
__global__ __launch_bounds__(256) void k_transpose_cvt(const float* __restrict__ in,
                                                       unsigned short* __restrict__ out,
                                                       int K, int N) {
  __shared__ float tile[32][33];
  int k0 = blockIdx.x * 32;
  int n0 = blockIdx.y * 32;
  int tx = threadIdx.x & 31, ty = threadIdx.x >> 5;   // ty 0..7
  #pragma unroll
  for (int r = ty; r < 32; r += 8)
    tile[r][tx] = in[(size_t)(k0 + r) * N + n0 + tx];
  __syncthreads();
  #pragma unroll
  for (int r = ty; r < 32; r += 8)
    out[(size_t)(n0 + r) * K + k0 + tx] = f2bf(tile[tx][r]);
}

// ---------------- fp32 -> bf16 elementwise (x) ----------------
__global__ __launch_bounds__(256) void k_cvt(const float* __restrict__ in,
                                             unsigned short* __restrict__ out, int n4) {
  int i = blockIdx.x * 256 + threadIdx.x;
  if (i >= n4) return;
  float4 v = ((const float4*)in)[i];
  ushort4 o;
  o.x = f2bf(v.x); o.y = f2bf(v.y); o.z = f2bf(v.z); o.w = f2bf(v.w);
  ((ushort4*)out)[i] = o;
}

// ---------------- bf16 GEMM, 8-phase template, BM=128, BN=NJ*64 (round-5 config) --------
template<int NJ, int EPI, int MMAJ>
__global__ __launch_bounds__(512, 1) void k_gemm8(const unsigned short* __restrict__ A,
                                                  const unsigned short* __restrict__ Bt,
                                                  float* __restrict__ C,
                                                  unsigned short* __restrict__ qo,
                                                  unsigned short* __restrict__ ko,
                                                  unsigned short* __restrict__ vo,
                                                  int M, int N, int K) {
  constexpr int BU = NJ / 2;             // B units of 128 rows
  constexpr int DSTRIDE = (1 + BU) * 16384;
  extern __shared__ __align__(16) char lds[];
  const int tid = threadIdx.x;
  const int lane = tid & 63;
  const int lr = lane & 15, lg = lane >> 4;
  const int wave = tid >> 6;
  const int wm = wave >> 2, wn = wave & 3;
  const int nwg = gridDim.x;
  const int bid = blockIdx.x;
  const int wg = (bid & 7) * (nwg >> 3) + (bid >> 3);
  const int GX = M >> 7;
  const int GN = N / (NJ * 64);
  const int mt = MMAJ ? (wg % GX) : (wg / GN);
  const int nt = MMAJ ? (wg / GX) : (wg % GN);
  const int m0 = mt * 128, n0 = nt * NJ * 64;
  const int NT = K >> 6;

  auto STAGE = [&](int d, int op, int h, int t) {
    const unsigned short* src = op ? Bt : A;
    const int r0 = (op ? n0 + h * 128 : m0);
    const int kc = t * 64;
    char* base = lds + d * DSTRIDE + op * 16384 + h * 16384;
    #pragma unroll
    for (int l = 0; l < 2; ++l) {
      int p = (l * 512 + tid) * 16;
      int qq = p ^ (((p >> 7) & 7) << 4);
      const unsigned short* g = src + (size_t)(r0 + (qq >> 7)) * K + kc + ((qq & 127) >> 1);
      __builtin_amdgcn_global_load_lds(
          (const __attribute__((address_space(1))) void*)g,
          (__attribute__((address_space(3))) void*)(base + (l * 512 + (tid & 448)) * 16),
          16, 0, 0);
    }
  };
  auto RD = [&](int d, int op, int row, int kb) -> bf16x8 {
    const char* base = lds + d * DSTRIDE + op * 16384;
    int p = row * 128 + kb;
    p ^= ((p >> 7) & 7) << 4;
    return *(const bf16x8*)(base + p);
  };

  f32x4 acc[4][NJ];
  #pragma unroll
  for (int i = 0; i < 4; ++i)
    #pragma unroll
    for (int j = 0; j < NJ; ++j) acc[i][j] = (f32x4){0.f, 0.f, 0.f, 0.f};

  bf16x8 bfrg[NJ][2];

#define PHASE(D, MI, READB, DOST, SD, SO, SH, ST, VM)                                    \
  {                                                                                      \
    if (READB) {                                                                         \
      _Pragma("unroll")                                                                  \
      for (int nj = 0; nj < NJ; ++nj)                                                    \
        _Pragma("unroll")                                                                \
        for (int ks = 0; ks < 2; ++ks)                                                   \
          bfrg[nj][ks] = RD(D, 1, wn * NJ * 16 + nj * 16 + lr, ks * 64 + lg * 16);       \
    }                                                                                    \
    bf16x8 af[2];                                                                        \
    _Pragma("unroll")                                                                    \
    for (int ks = 0; ks < 2; ++ks)                                                       \
      af[ks] = RD(D, 0, wm * 64 + (MI) * 16 + lr, ks * 64 + lg * 16);                    \
    if (DOST) STAGE(SD, SO, SH, ST);                                                     \
    __builtin_amdgcn_s_barrier();                                                        \
    asm volatile("s_waitcnt lgkmcnt(0)" ::: "memory");                                   \
    __builtin_amdgcn_s_setprio(1);                                                       \
    _Pragma("unroll")                                                                    \
    for (int nj = 0; nj < NJ; ++nj)                                                      \
      _Pragma("unroll")                                                                  \
      for (int ks = 0; ks < 2; ++ks)                                                     \
        acc[MI][nj] = __builtin_amdgcn_mfma_f32_16x16x32_bf16(af[ks], bfrg[nj][ks], acc[MI][nj], 0, 0, 0); \
    __builtin_amdgcn_s_setprio(0);                                                       \
    if ((VM) == 6) asm volatile("s_waitcnt vmcnt(6)" ::: "memory");                      \
    if ((VM) == 4) asm volatile("s_waitcnt vmcnt(4)" ::: "memory");                      \
    __builtin_amdgcn_s_barrier();                                                        \
  }

  const int t1 = NT > 1 ? 1 : 0;
  #pragma unroll
  for (int h = 0; h < BU; ++h) STAGE(0, 1, h, 0);
  STAGE(0, 0, 0, 0);
  #pragma unroll
  for (int h = 0; h < BU; ++h) STAGE(1, 1, h, t1);
  if (NJ == 6) asm volatile("s_waitcnt vmcnt(6)" ::: "memory");
  else         asm volatile("s_waitcnt vmcnt(4)" ::: "memory");
  __builtin_amdgcn_s_barrier();

  for (int it = 0; it < (NT >> 1); ++it) {
    const int tb  = 2 * it + 1;
    const int ta1 = min(2 * it + 2, NT - 1);
    const int tb1 = min(2 * it + 3, NT - 1);
    if (NJ == 6) {
      PHASE(0, 0, true,  true, 1, 0, 0, tb,  -1)
      PHASE(0, 1, false, true, 0, 1, 0, ta1, -1)
      PHASE(0, 2, false, true, 0, 1, 1, ta1, -1)
      PHASE(0, 3, false, true, 0, 1, 2, ta1,  6)
      PHASE(1, 0, true,  true, 0, 0, 0, ta1, -1)
      PHASE(1, 1, false, true, 1, 1, 0, tb1, -1)
      PHASE(1, 2, false, true, 1, 1, 1, tb1, -1)
      PHASE(1, 3, false, true, 1, 1, 2, tb1,  6)
    } else {
      PHASE(0, 0, true,  true,  1, 0, 0, tb,  -1)
      PHASE(0, 1, false, true,  0, 1, 0, ta1, -1)
      PHASE(0, 2, false, true,  0, 1, 1, ta1, -1)
      PHASE(0, 3, false, false, 0, 0, 0, 0,    4)
      PHASE(1, 0, true,  true,  0, 0, 0, ta1, -1)
      PHASE(1, 1, false, true,  1, 1, 0, tb1, -1)
      PHASE(1, 2, false, true,  1, 1, 1, tb1, -1)
      PHASE(1, 3, false, false, 0, 0, 0, 0,    4)
    }
  }
#undef PHASE

  #pragma unroll
  for (int mi = 0; mi < 4; ++mi) {
    #pragma unroll
    for (int nj = 0; nj < NJ; ++nj) {
      #pragma unroll
      for (int j = 0; j < 4; ++j) {
        int m = m0 + wm * 64 + mi * 16 + lg * 4 + j;
        int n = n0 + wn * NJ * 16 + nj * 16 + lr;
        float val = acc[mi][nj][j];
        if (EPI == 0) {
          C[(size_t)m * N + n] = val;
        } else {
          int which = n >> 11, cc = n & 2047;
          int h = cc >> 7, d = cc & 127;
          int b = m >> 11, t = m & 2047;
          unsigned short* dst = which == 0 ? qo : (which == 1 ? ko : vo);
          dst[(((size_t)(b * NH + h)) * T_SEQ + t) * HD + d] = f2bf(val);
        }
      }
    }
  }
}

// ---------------- RoPE in place on q (scaled by 1/sqrt(D)) and k ----------------
__global__ __launch_bounds__(256) void k_rope(unsigned short* __restrict__ q,
                                              unsigned short* __restrict__ k) {
  int i = blockIdx.x * 256 + threadIdx.x;   // over 32 * 2048 * 64
  int d = i & 63;
  int t = (i >> 6) & (T_SEQ - 1);
  int bh = i >> 17;
  float invf = exp2f((float)(-2 * d) * (13.287712379549449f / 128.f)); // 10000^(-2d/128)
  float ang = (float)t * invf;
  float c = cosf(ang), s = sinf(ang);
  size_t base = ((size_t)bh * T_SEQ + t) * HD + d;
  const float scale = 0.08838834764831845f;  // 1/sqrt(128)
  float q1 = bf2f(q[base]), q2 = bf2f(q[base + 64]);
  q[base]      = f2bf((q1 * c - q2 * s) * scale);
  q[base + 64] = f2bf((q2 * c + q1 * s) * scale);
  float k1 = bf2f(k[base]), k2 = bf2f(k[base + 64]);
  k[base]      = f2bf(k1 * c - k2 * s);
  k[base + 64] = f2bf(k2 * c + k1 * s);
}

// ---------------- bf16 transpose per (b,h): (T,D) -> (D,T) ----------------
__global__ __launch_bounds__(256) void k_transpose_v(const unsigned short* __restrict__ in,
                                                     unsigned short* __restrict__ out) {
  __shared__ unsigned short tile[32][33];
  int bh = blockIdx.z;
  int t0 = blockIdx.x * 32, d0 = blockIdx.y * 32;
  int tx = threadIdx.x & 31, ty = threadIdx.x >> 5;
  const unsigned short* src = in + (size_t)bh * T_SEQ * HD;
  unsigned short* dst = out + (size_t)bh * HD * T_SEQ;
  #pragma unroll
  for (int r = ty; r < 32; r += 8)
    tile[r][tx] = src[(size_t)(t0 + r) * HD + d0 + tx];
  __syncthreads();
  #pragma unroll
  for (int r = ty; r < 32; r += 8)
    dst[(size_t)(d0 + r) * T_SEQ + t0 + tx] = tile[tx][r];
}

// ---------------- causal flash attention: 4 waves x 32 Q-rows (2 groups), LDS K/V --------
// Q,K: (B*H, T, D) bf16 (q pre-scaled).  Vt: (B*H, D, T) bf16.  Y: (B, T, C) bf16.
// Each K/V fragment read from LDS feeds 2 MFMAs (one per row-group) -> ~36 ds_reads
// per 64 MFMA vs 34/32 before. 128-row Q-tile per block, K/V tile 64.
// Grid 512: id & id+256 share bh (L2 reuse), qtl complements (per-CU balance), heavy first.
__global__ __launch_bounds__(256, 2) void k_attn(const unsigned short* __restrict__ Q,
                                                 const unsigned short* __restrict__ K,
                                                 const unsigned short* __restrict__ Vt,
                                                 unsigned short* __restrict__ Y) {
  __shared__ __align__(16) unsigned short Ks[64 * 128];   // XOR-swizzled
  __shared__ __align__(16) unsigned short Vs[128 * 64];   // XOR-swizzled
  __shared__ __align__(16) unsigned short Ps[128 * 80];   // padded rows (160B)
  const int id = blockIdx.x;            // 0..511
  const int sub = id & 255;
  const int bh = sub & 31;
  const int qtl = (id < 256) ? (15 - (sub >> 5)) : (sub >> 5);
  const int b = bh >> 4, h = bh & 15;
  const int tid = threadIdx.x, wave = tid >> 6, lane = tid & 63;
  const int lr = lane & 15, lg = lane >> 4;
  const int q0 = qtl * 128;
  const int jtmax = 2 * qtl + 1;
  const unsigned short* Qb = Q + (size_t)bh * T_SEQ * HD;
  const unsigned short* Kb = K + (size_t)bh * T_SEQ * HD;
  const unsigned short* Vb = Vt + (size_t)bh * HD * T_SEQ;

  // staging geometry (256 threads cover K 16KB + V 16KB in 4 chunks each)
  int rkA[4], okA[4], rvA[4], ovA[4], bkA[4], bvA[4];
  #pragma unroll
  for (int it = 0; it < 4; ++it) {
    int c = it * 256 + tid;
    rkA[it] = c >> 4; okA[it] = (c & 15) * 8;
    bkA[it] = (rkA[it] * 256 + (c & 15) * 16) ^ ((rkA[it] & 7) << 4);
    rvA[it] = c >> 3; ovA[it] = (c & 7) * 8;
    bvA[it] = (rvA[it] * 128 + (c & 7) * 16) ^ ((rvA[it] & 7) << 4);
  }

  // hoist Q fragments: wave's 32 rows = 2 groups x 16, 4 K-slices of 32
  bf16x8 qf[2][4];
  #pragma unroll
  for (int g = 0; g < 2; ++g)
    #pragma unroll
    for (int kk = 0; kk < 4; ++kk)
      qf[g][kk] = *(const bf16x8*)(Qb + (size_t)(q0 + wave * 32 + g * 16 + lr) * HD + kk * 32 + lg * 8);

  const f32x4 fzero = {0.f, 0.f, 0.f, 0.f};
  f32x4 oacc[2][8];
  #pragma unroll
  for (int g = 0; g < 2; ++g)
    #pragma unroll
    for (int nd = 0; nd < 8; ++nd) oacc[g][nd] = fzero;
  float mrow[2][4], lrow[2][4];
  #pragma unroll
  for (int g = 0; g < 2; ++g)
    #pragma unroll
    for (int j = 0; j < 4; ++j) { mrow[g][j] = -1e30f; lrow[g][j] = 0.f; }

  // prologue: prefetch tile 0 into registers
  bf16x8 kst[4], vst[4];
  #pragma unroll
  for (int it = 0; it < 4; ++it) {
    kst[it] = *(const bf16x8*)(Kb + (size_t)rkA[it] * HD + okA[it]);
    vst[it] = *(const bf16x8*)(Vb + (size_t)rvA[it] * T_SEQ + ovA[it]);
  }

  for (int jt = 0; jt <= jtmax; ++jt) {
    const int tk0 = jt * 64;
    __syncthreads();   // previous iteration's LDS reads done
    #pragma unroll
    for (int it = 0; it < 4; ++it) {
      *(bf16x8*)((char*)Ks + bkA[it]) = kst[it];
      *(bf16x8*)((char*)Vs + bvA[it]) = vst[it];
    }
    if (jt < jtmax) {
      const int nk0 = tk0 + 64;
      #pragma unroll
      for (int it = 0; it < 4; ++it) {
        kst[it] = *(const bf16x8*)(Kb + (size_t)(nk0 + rkA[it]) * HD + okA[it]);
        vst[it] = *(const bf16x8*)(Vb + (size_t)rvA[it] * T_SEQ + nk0 + ovA[it]);
      }
    }
    __syncthreads();   // LDS tile ready

    // S = Q K^T : each K frag feeds both row-groups
    f32x4 sacc[2][4];
    #pragma unroll
    for (int g = 0; g < 2; ++g)
      #pragma unroll
      for (int nr = 0; nr < 4; ++nr) sacc[g][nr] = fzero;
    __builtin_amdgcn_s_setprio(1);
    #pragma unroll
    for (int nr = 0; nr < 4; ++nr) {
      #pragma unroll
      for (int kk = 0; kk < 4; ++kk) {
        int row = nr * 16 + lr;
        int byte = (row * 256 + kk * 64 + lg * 16) ^ ((row & 7) << 4);
        bf16x8 kf = *(const bf16x8*)((char*)Ks + byte);
        sacc[0][nr] = __builtin_amdgcn_mfma_f32_16x16x32_bf16(qf[0][kk], kf, sacc[0][nr], 0, 0, 0);
        sacc[1][nr] = __builtin_amdgcn_mfma_f32_16x16x32_bf16(qf[1][kk], kf, sacc[1][nr], 0, 0, 0);
      }
    }
    __builtin_amdgcn_s_setprio(0);

    if (jt >= 2 * qtl) {  // diagonal region: causal mask
      #pragma unroll
      for (int g = 0; g < 2; ++g)
        #pragma unroll
        for (int nr = 0; nr < 4; ++nr)
          #pragma unroll
          for (int j = 0; j < 4; ++j) {
            int qg = q0 + wave * 32 + g * 16 + lg * 4 + j;
            int cg = tk0 + nr * 16 + lr;
            if (cg > qg) sacc[g][nr][j] = -1e30f;
          }
    }

    // online softmax per group (row = lg*4+j, 16 lanes share a row)
    #pragma unroll
    for (int g = 0; g < 2; ++g) {
      float oscale[4];
      #pragma unroll
      for (int j = 0; j < 4; ++j) {
        float tmax = fmaxf(fmaxf(sacc[g][0][j], sacc[g][1][j]), fmaxf(sacc[g][2][j], sacc[g][3][j]));
        #pragma unroll
        for (int m = 1; m <= 8; m <<= 1) tmax = fmaxf(tmax, __shfl_xor(tmax, m));
        float mnew = fmaxf(mrow[g][j], tmax);
        oscale[j] = __expf(mrow[g][j] - mnew);
        float rsum = 0.f;
        #pragma unroll
        for (int nr = 0; nr < 4; ++nr) {
          float p = __expf(sacc[g][nr][j] - mnew);
          Ps[(wave * 32 + g * 16 + lg * 4 + j) * 80 + nr * 16 + lr] = f2bf(p);
          rsum += p;
        }
        #pragma unroll
        for (int m = 1; m <= 8; m <<= 1) rsum += __shfl_xor(rsum, m);
        lrow[g][j] = lrow[g][j] * oscale[j] + rsum;
        mrow[g][j] = mnew;
      }
      #pragma unroll
      for (int nd = 0; nd < 8; ++nd)
        #pragma unroll
        for (int j = 0; j < 4; ++j) oacc[g][nd][j] *= oscale[j];
    }

    // PV: each V frag feeds both row-groups (P strips wave-local; DS in-order per wave)
    bf16x8 pf[2][2];
    #pragma unroll
    for (int g = 0; g < 2; ++g)
      #pragma unroll
      for (int kk = 0; kk < 2; ++kk)
        pf[g][kk] = *(const bf16x8*)(Ps + (wave * 32 + g * 16 + lr) * 80 + kk * 32 + lg * 8);
    __builtin_amdgcn_s_setprio(1);
    #pragma unroll
    for (int nd = 0; nd < 8; ++nd) {
      #pragma unroll
      for (int kk = 0; kk < 2; ++kk) {
        int row = nd * 16 + lr;
        int byte = (row * 128 + kk * 64 + lg * 16) ^ ((row & 7) << 4);
        bf16x8 vf = *(const bf16x8*)((char*)Vs + byte);
        oacc[0][nd] = __builtin_amdgcn_mfma_f32_16x16x32_bf16(pf[0][kk], vf, oacc[0][nd], 0, 0, 0);
        oacc[1][nd] = __builtin_amdgcn_mfma_f32_16x16x32_bf16(pf[1][kk], vf, oacc[1][nd], 0, 0, 0);
      }
    }
    __builtin_amdgcn_s_setprio(0);
  }

  // epilogue: O / l -> Y (B,T,C)
  #pragma unroll
  for (int g = 0; g < 2; ++g)
    #pragma unroll
    for (int j = 0; j < 4; ++j) {
      float inv = 1.f / lrow[g][j];
      int qg = q0 + wave * 32 + g * 16 + lg * 4 + j;
      size_t base = ((size_t)b * T_SEQ + qg) * CC + h * HD;
      #pragma unroll
      for (int nd = 0; nd < 8; ++nd)
        Y[base + nd * 16 + lr] = f2bf(oacc[g][nd][j] * inv);
    }
}

extern "C" void kernel_launch(void* const* d_in, const int* in_sizes, int n_in,
                              void* d_out, int out_size, void* d_ws, size_t ws_size,
                              hipStream_t stream) {
  const float* x     = (const float*)d_in[0];
  const float* Wqkv  = (const float*)d_in[1];
  const float* Wproj = (const float*)d_in[2];
  float* out = (float*)d_out;
  char* ws = (char*)d_ws;
  const size_t MB = 1024 * 1024;
  unsigned short* WqkvT  = (unsigned short*)(ws + 0);        // 24MB; dead after GEMM1
  unsigned short* vt     = (unsigned short*)(ws + 0);        // 16MB, aliases WqkvT
  unsigned short* WprojT = (unsigned short*)(ws + 24 * MB);  // 8MB
  unsigned short* xb     = (unsigned short*)(ws + 32 * MB);  // 16MB; dead after GEMM1
  unsigned short* y      = xb;                               // aliases xb
  unsigned short* q      = (unsigned short*)(ws + 48 * MB);  // 16MB
  unsigned short* k      = (unsigned short*)(ws + 64 * MB);  // 16MB
  unsigned short* v      = (unsigned short*)(ws + 80 * MB);  // 16MB  (total 96MB)

  k_transpose_cvt<<<dim3(CC / 32, N3 / 32), 256, 0, stream>>>(Wqkv, WqkvT, CC, N3);
  k_transpose_cvt<<<dim3(CC / 32, CC / 32), 256, 0, stream>>>(Wproj, WprojT, CC, CC);
  k_cvt<<<(MM * CC / 4) / 256, 256, 0, stream>>>(x, xb, MM * CC / 4);
  // GEMM1: 4096 x 6144 x 2048, BM=128 BN=384 -> grid 512 (exactly 2 gens), m-major chunks
  k_gemm8<6, 1, 1><<<dim3((MM / 128) * (N3 / 384)), 512, 131072, stream>>>(
      xb, WqkvT, nullptr, q, k, v, MM, N3, CC);
  k_rope<<<(32 * T_SEQ * 64) / 256, 256, 0, stream>>>(q, k);
  k_transpose_v<<<dim3(T_SEQ / 32, HD / 32, 32), 256, 0, stream>>>(v, vt);
  k_attn<<<dim3(512), 256, 0, stream>>>(q, k, vt, y);
  // GEMM2: 4096 x 2048 x 2048, BM=128 BN=256 -> grid 256 (exactly 1/CU), n-major chunks
  k_gemm8<4, 0, 0><<<dim3((MM / 128) * (CC / 256)), 512, 98304, stream>>>(
      y, WprojT, out, nullptr, nullptr, nullptr, MM, CC, CC);
}

// Round 10
// 271.142 us; speedup vs baseline: 1.6638x; 1.1213x over previous
//
#include <hip/hip_runtime.h>
#include <stdint.h>

#define T_SEQ 2048
#define NH 16
#define HD 128
#define CC 2048
#define N3 6144
#define MM 4096   // B*T

typedef short bf16x8 __attribute__((ext_vector_type(8)));
typedef float f32x4 __attribute__((ext_vector_type(4)));
typedef float f32x16 __attribute__((ext_vector_type(16)));
typedef unsigned int u32x4 __attribute__((ext_vector_type(4)));

__device__ __forceinline__ unsigned short f2bf(float f) {
  unsigned int u = __float_as_uint(f);
  u += 0x7FFF + ((u >> 16) & 1);   // RNE
  return (unsigned short)(u >> 16);
}
__device__ __forceinline__ float bf2f(unsigned short h) {
  return __uint_as_float(((unsigned int)h) << 16);
}
__device__ __forceinline__ unsigned int cvt_pk_bf16(float lo, float hi) {
  unsigned int r;
  asm("v_cvt_pk_bf16_f32 %0, %1, %2" : "=v"(r) : "v"(lo), "v"(hi));
  return r;
}

// ---------------- transpose + fp32->bf16 convert: out[n][k] = in[k][n] ----------------
__global__ __launch_bounds__(256) void k_transpose_cvt(const float* __restrict__ in,
                                                       unsigned short* __restrict__ out,
                                                       int K, int N) {
  __shared__ float tile[32][33];
  int k0 = blockIdx.x * 32;
  int n0 = blockIdx.y * 32;
  int tx = threadIdx.x & 31, ty = threadIdx.x >> 5;   // ty 0..7
  #pragma unroll
  for (int r = ty; r < 32; r += 8)
    tile[r][tx] = in[(size_t)(k0 + r) * N + n0 + tx];
  __syncthreads();
  #pragma unroll
  for (int r = ty; r < 32; r += 8)
    out[(size_t)(n0 + r) * K + k0 + tx] = f2bf(tile[tx][r]);
}

// ---------------- fp32 -> bf16 elementwise (x) ----------------
__global__ __launch_bounds__(256) void k_cvt(const float* __restrict__ in,
                                             unsigned short* __restrict__ out, int n4) {
  int i = blockIdx.x * 256 + threadIdx.x;
  if (i >= n4) return;
  float4 v = ((const float4*)in)[i];
  ushort4 o;
  o.x = f2bf(v.x); o.y = f2bf(v.y); o.z = f2bf(v.z); o.w = f2bf(v.w);
  ((ushort4*)out)[i] = o;
}

// ---------------- bf16 GEMM, 8-phase template, BM=128, BN=NJ*64 (round-5 config) --------
template<int NJ, int EPI, int MMAJ>
__global__ __launch_bounds__(512, 1) void k_gemm8(const unsigned short* __restrict__ A,
                                                  const unsigned short* __restrict__ Bt,
                                                  float* __restrict__ C,
                                                  unsigned short* __restrict__ qo,
                                                  unsigned short* __restrict__ ko,
                                                  unsigned short* __restrict__ vo,
                                                  int M, int N, int K) {
  constexpr int BU = NJ / 2;             // B units of 128 rows
  constexpr int DSTRIDE = (1 + BU) * 16384;
  extern __shared__ __align__(16) char lds[];
  const int tid = threadIdx.x;
  const int lane = tid & 63;
  const int lr = lane & 15, lg = lane >> 4;
  const int wave = tid >> 6;
  const int wm = wave >> 2, wn = wave & 3;
  const int nwg = gridDim.x;
  const int bid = blockIdx.x;
  const int wg = (bid & 7) * (nwg >> 3) + (bid >> 3);
  const int GX = M >> 7;
  const int GN = N / (NJ * 64);
  const int mt = MMAJ ? (wg % GX) : (wg / GN);
  const int nt = MMAJ ? (wg / GX) : (wg % GN);
  const int m0 = mt * 128, n0 = nt * NJ * 64;
  const int NT = K >> 6;

  auto STAGE = [&](int d, int op, int h, int t) {
    const unsigned short* src = op ? Bt : A;
    const int r0 = (op ? n0 + h * 128 : m0);
    const int kc = t * 64;
    char* base = lds + d * DSTRIDE + op * 16384 + h * 16384;
    #pragma unroll
    for (int l = 0; l < 2; ++l) {
      int p = (l * 512 + tid) * 16;
      int qq = p ^ (((p >> 7) & 7) << 4);
      const unsigned short* g = src + (size_t)(r0 + (qq >> 7)) * K + kc + ((qq & 127) >> 1);
      __builtin_amdgcn_global_load_lds(
          (const __attribute__((address_space(1))) void*)g,
          (__attribute__((address_space(3))) void*)(base + (l * 512 + (tid & 448)) * 16),
          16, 0, 0);
    }
  };
  auto RD = [&](int d, int op, int row, int kb) -> bf16x8 {
    const char* base = lds + d * DSTRIDE + op * 16384;
    int p = row * 128 + kb;
    p ^= ((p >> 7) & 7) << 4;
    return *(const bf16x8*)(base + p);
  };

  f32x4 acc[4][NJ];
  #pragma unroll
  for (int i = 0; i < 4; ++i)
    #pragma unroll
    for (int j = 0; j < NJ; ++j) acc[i][j] = (f32x4){0.f, 0.f, 0.f, 0.f};

  bf16x8 bfrg[NJ][2];

#define PHASE(D, MI, READB, DOST, SD, SO, SH, ST, VM)                                    \
  {                                                                                      \
    if (READB) {                                                                         \
      _Pragma("unroll")                                                                  \
      for (int nj = 0; nj < NJ; ++nj)                                                    \
        _Pragma("unroll")                                                                \
        for (int ks = 0; ks < 2; ++ks)                                                   \
          bfrg[nj][ks] = RD(D, 1, wn * NJ * 16 + nj * 16 + lr, ks * 64 + lg * 16);       \
    }                                                                                    \
    bf16x8 af[2];                                                                        \
    _Pragma("unroll")                                                                    \
    for (int ks = 0; ks < 2; ++ks)                                                       \
      af[ks] = RD(D, 0, wm * 64 + (MI) * 16 + lr, ks * 64 + lg * 16);                    \
    if (DOST) STAGE(SD, SO, SH, ST);                                                     \
    __builtin_amdgcn_s_barrier();                                                        \
    asm volatile("s_waitcnt lgkmcnt(0)" ::: "memory");                                   \
    __builtin_amdgcn_s_setprio(1);                                                       \
    _Pragma("unroll")                                                                    \
    for (int nj = 0; nj < NJ; ++nj)                                                      \
      _Pragma("unroll")                                                                  \
      for (int ks = 0; ks < 2; ++ks)                                                     \
        acc[MI][nj] = __builtin_amdgcn_mfma_f32_16x16x32_bf16(af[ks], bfrg[nj][ks], acc[MI][nj], 0, 0, 0); \
    __builtin_amdgcn_s_setprio(0);                                                       \
    if ((VM) == 6) asm volatile("s_waitcnt vmcnt(6)" ::: "memory");                      \
    if ((VM) == 4) asm volatile("s_waitcnt vmcnt(4)" ::: "memory");                      \
    __builtin_amdgcn_s_barrier();                                                        \
  }

  const int t1 = NT > 1 ? 1 : 0;
  #pragma unroll
  for (int h = 0; h < BU; ++h) STAGE(0, 1, h, 0);
  STAGE(0, 0, 0, 0);
  #pragma unroll
  for (int h = 0; h < BU; ++h) STAGE(1, 1, h, t1);
  if (NJ == 6) asm volatile("s_waitcnt vmcnt(6)" ::: "memory");
  else         asm volatile("s_waitcnt vmcnt(4)" ::: "memory");
  __builtin_amdgcn_s_barrier();

  for (int it = 0; it < (NT >> 1); ++it) {
    const int tb  = 2 * it + 1;
    const int ta1 = min(2 * it + 2, NT - 1);
    const int tb1 = min(2 * it + 3, NT - 1);
    if (NJ == 6) {
      PHASE(0, 0, true,  true, 1, 0, 0, tb,  -1)
      PHASE(0, 1, false, true, 0, 1, 0, ta1, -1)
      PHASE(0, 2, false, true, 0, 1, 1, ta1, -1)
      PHASE(0, 3, false, true, 0, 1, 2, ta1,  6)
      PHASE(1, 0, true,  true, 0, 0, 0, ta1, -1)
      PHASE(1, 1, false, true, 1, 1, 0, tb1, -1)
      PHASE(1, 2, false, true, 1, 1, 1, tb1, -1)
      PHASE(1, 3, false, true, 1, 1, 2, tb1,  6)
    } else {
      PHASE(0, 0, true,  true,  1, 0, 0, tb,  -1)
      PHASE(0, 1, false, true,  0, 1, 0, ta1, -1)
      PHASE(0, 2, false, true,  0, 1, 1, ta1, -1)
      PHASE(0, 3, false, false, 0, 0, 0, 0,    4)
      PHASE(1, 0, true,  true,  0, 0, 0, ta1, -1)
      PHASE(1, 1, false, true,  1, 1, 0, tb1, -1)
      PHASE(1, 2, false, true,  1, 1, 1, tb1, -1)
      PHASE(1, 3, false, false, 0, 0, 0, 0,    4)
    }
  }
#undef PHASE

  #pragma unroll
  for (int mi = 0; mi < 4; ++mi) {
    #pragma unroll
    for (int nj = 0; nj < NJ; ++nj) {
      #pragma unroll
      for (int j = 0; j < 4; ++j) {
        int m = m0 + wm * 64 + mi * 16 + lg * 4 + j;
        int n = n0 + wn * NJ * 16 + nj * 16 + lr;
        float val = acc[mi][nj][j];
        if (EPI == 0) {
          C[(size_t)m * N + n] = val;
        } else {
          int which = n >> 11, cc = n & 2047;
          int h = cc >> 7, d = cc & 127;
          int b = m >> 11, t = m & 2047;
          unsigned short* dst = which == 0 ? qo : (which == 1 ? ko : vo);
          dst[(((size_t)(b * NH + h)) * T_SEQ + t) * HD + d] = f2bf(val);
        }
      }
    }
  }
}

// ---------------- RoPE in place on q (scaled by log2e/sqrt(D)) and k ----------------
__global__ __launch_bounds__(256) void k_rope(unsigned short* __restrict__ q,
                                              unsigned short* __restrict__ k) {
  int i = blockIdx.x * 256 + threadIdx.x;   // over 32 * 2048 * 64
  int d = i & 63;
  int t = (i >> 6) & (T_SEQ - 1);
  int bh = i >> 17;
  float invf = exp2f((float)(-2 * d) * (13.287712379549449f / 128.f)); // 10000^(-2d/128)
  float ang = (float)t * invf;
  float c = cosf(ang), s = sinf(ang);
  size_t base = ((size_t)bh * T_SEQ + t) * HD + d;
  const float scale = 0.12751741562076117f;  // log2(e)/sqrt(128): attn uses exp2
  float q1 = bf2f(q[base]), q2 = bf2f(q[base + 64]);
  q[base]      = f2bf((q1 * c - q2 * s) * scale);
  q[base + 64] = f2bf((q2 * c + q1 * s) * scale);
  float k1 = bf2f(k[base]), k2 = bf2f(k[base + 64]);
  k[base]      = f2bf(k1 * c - k2 * s);
  k[base + 64] = f2bf(k2 * c + k1 * s);
}

// ---------------- bf16 transpose per (b,h): (T,D) -> (D,T) ----------------
__global__ __launch_bounds__(256) void k_transpose_v(const unsigned short* __restrict__ in,
                                                     unsigned short* __restrict__ out) {
  __shared__ unsigned short tile[32][33];
  int bh = blockIdx.z;
  int t0 = blockIdx.x * 32, d0 = blockIdx.y * 32;
  int tx = threadIdx.x & 31, ty = threadIdx.x >> 5;
  const unsigned short* src = in + (size_t)bh * T_SEQ * HD;
  unsigned short* dst = out + (size_t)bh * HD * T_SEQ;
  #pragma unroll
  for (int r = ty; r < 32; r += 8)
    tile[r][tx] = src[(size_t)(t0 + r) * HD + d0 + tx];
  __syncthreads();
  #pragma unroll
  for (int r = ty; r < 32; r += 8)
    dst[(size_t)(d0 + r) * T_SEQ + t0 + tx] = tile[tx][r];
}

// ---------------- causal flash attention: swapped QK^T, 32x32 MFMA, in-register softmax --
// Q,K: (B*H, T, D) bf16 (q pre-scaled by log2e/sqrt(D)).  Vt: (B*H, D, T).  Y: (B,T,C).
// 4 waves x 32 q-rows (QBLK=128), KVBLK=64. S^T = mfma(K, Q): lane owns one q-row ->
// softmax lane-local (31 fmax + xor-32 exchange). P stays in-register (cvt_pk + xor-32
// redistribution feeds PV's A-operand). K/V in dbuf XOR-swizzled LDS (pre-swizzled
// global_load_lds source). One barrier + vmcnt(0) per tile. Defer-max THR=8 (log2 domain).
__global__ __launch_bounds__(256, 2) void k_attn(const unsigned short* __restrict__ Q,
                                                 const unsigned short* __restrict__ K,
                                                 const unsigned short* __restrict__ Vt,
                                                 unsigned short* __restrict__ Y) {
  __shared__ __align__(16) unsigned short Kls[2][64 * 128];   // [buf][k][d] swizzled
  __shared__ __align__(16) unsigned short Vls[2][128 * 64];   // [buf][d][k] swizzled
  const int id = blockIdx.x;            // 0..511
  const int sub = id & 255;
  const int bh = sub & 31;
  const int qtl = (id < 256) ? (15 - (sub >> 5)) : (sub >> 5);  // heavy first; pairs balance
  const int b = bh >> 4, h = bh & 15;
  const int tid = threadIdx.x, wv = tid >> 6, lane = tid & 63;
  const int l31 = lane & 31, hh = lane >> 5;
  const int q0 = qtl * 128;
  const int jtmax = 2 * qtl + 1;
  const int qglob = q0 + wv * 32 + l31;
  const unsigned short* Qb = Q + (size_t)bh * T_SEQ * HD;
  const unsigned short* Kb = K + (size_t)bh * T_SEQ * HD;
  const unsigned short* Vb = Vt + (size_t)bh * HD * T_SEQ;

  // stage K (64x128) + V^T (128x64) of tile tk into buf bb; source pre-swizzled (rule 21)
  auto STAGEKV = [&](int tk, int bb) {
    #pragma unroll
    for (int ch = 0; ch < 4; ++ch) {
      int p = (ch * 256 + tid) * 16;
      int q = p ^ (((p >> 8) & 7) << 4);
      const unsigned short* g = Kb + (size_t)(tk + (q >> 8)) * HD + ((q & 255) >> 1);
      __builtin_amdgcn_global_load_lds(
          (const __attribute__((address_space(1))) void*)g,
          (__attribute__((address_space(3))) void*)((char*)Kls[bb] + (ch * 256 + (tid & 192)) * 16),
          16, 0, 0);
    }
    #pragma unroll
    for (int ch = 0; ch < 4; ++ch) {
      int p = (ch * 256 + tid) * 16;
      int q = p ^ (((p >> 7) & 7) << 4);
      const unsigned short* g = Vb + (size_t)(q >> 7) * T_SEQ + tk + ((q & 127) >> 1);
      __builtin_amdgcn_global_load_lds(
          (const __attribute__((address_space(1))) void*)g,
          (__attribute__((address_space(3))) void*)((char*)Vls[bb] + (ch * 256 + (tid & 192)) * 16),
          16, 0, 0);
    }
  };

  // hoist Q: 8 d-chunks; B-operand layout: row q=l31, k(d) = hh*8 within chunk
  bf16x8 qfr[8];
  #pragma unroll
  for (int c = 0; c < 8; ++c)
    qfr[c] = *(const bf16x8*)(Qb + (size_t)qglob * HD + c * 16 + hh * 8);

  f32x16 oacc[4];
  #pragma unroll
  for (int dt = 0; dt < 4; ++dt)
    #pragma unroll
    for (int r = 0; r < 16; ++r) oacc[dt][r] = 0.f;
  float mrun = -1e30f, lrun = 0.f;

  STAGEKV(0, 0);
  asm volatile("s_waitcnt vmcnt(0)" ::: "memory");
  __syncthreads();

  for (int jt = 0; jt <= jtmax; ++jt) {
    const int cur = jt & 1;
    if (jt < jtmax) STAGEKV((jt + 1) * 64, cur ^ 1);

    // S^T = K Q^T : 2 k-tiles x 8 d-steps.  A=K frag: row k=t*32+l31, d = s*16+hh*8
    f32x16 sacc[2];
    #pragma unroll
    for (int t = 0; t < 2; ++t)
      #pragma unroll
      for (int r = 0; r < 16; ++r) sacc[t][r] = 0.f;
    __builtin_amdgcn_s_setprio(1);
    #pragma unroll
    for (int s = 0; s < 8; ++s) {
      #pragma unroll
      for (int t = 0; t < 2; ++t) {
        int row = t * 32 + l31;
        int byte = (row * 256 + s * 32 + hh * 16) ^ ((row & 7) << 4);
        bf16x8 kf = *(const bf16x8*)((const char*)Kls[cur] + byte);
        sacc[t] = __builtin_amdgcn_mfma_f32_32x32x16_bf16(kf, qfr[s], sacc[t], 0, 0, 0);
      }
    }
    __builtin_amdgcn_s_setprio(0);

    if (jt >= 2 * qtl) {  // diagonal: causal mask.  k row of reg r: (r&3)+8*(r>>2)+4*hh
      #pragma unroll
      for (int t = 0; t < 2; ++t)
        #pragma unroll
        for (int r = 0; r < 16; ++r) {
          int kg = jt * 64 + t * 32 + (r & 3) + 8 * (r >> 2) + 4 * hh;
          if (kg > qglob) sacc[t][r] = -1e30f;
        }
    }

    // lane-local max over 32 values + cross-32 exchange
    float pmax = sacc[0][0];
    #pragma unroll
    for (int r = 1; r < 16; ++r) pmax = fmaxf(pmax, sacc[0][r]);
    #pragma unroll
    for (int r = 0; r < 16; ++r) pmax = fmaxf(pmax, sacc[1][r]);
    pmax = fmaxf(pmax, __shfl_xor(pmax, 32));

    if (__any(pmax > mrun + 8.0f)) {   // defer-max: rescale only on real growth (T13)
      float mnew = fmaxf(mrun, pmax);
      float osc = exp2f(mrun - mnew);
      lrun *= osc;
      mrun = mnew;
      #pragma unroll
      for (int r = 0; r < 16; ++r) {
        int qr = (r & 3) + 8 * (r >> 2) + 4 * hh;
        float sr = __shfl(osc, qr);    // oacc rows are q-indexed; osc lives in lane q
        #pragma unroll
        for (int dt = 0; dt < 4; ++dt) oacc[dt][r] *= sr;
      }
    }

    // P = exp2(S - m), packed to bf16 pairs; row-sum
    unsigned int pk[16];
    float rsum = 0.f;
    #pragma unroll
    for (int t = 0; t < 2; ++t)
      #pragma unroll
      for (int i = 0; i < 8; ++i) {
        float p0 = exp2f(sacc[t][2 * i] - mrun);
        float p1 = exp2f(sacc[t][2 * i + 1] - mrun);
        rsum += p0 + p1;
        pk[t * 8 + i] = cvt_pk_bf16(p0, p1);
      }
    rsum += __shfl_xor(rsum, 32);
    lrun += rsum;

    // redistribute P into A-operand frags: chunk c covers k = c*16..c*16+15
    bf16x8 pa[4];
    #pragma unroll
    for (int c = 0; c < 4; ++c) {
      int base = (c >> 1) * 8 + (c & 1) * 4;
      unsigned int s0 = hh == 0 ? pk[base + 2] : pk[base + 0];
      unsigned int s1 = hh == 0 ? pk[base + 3] : pk[base + 1];
      unsigned int r0 = __shfl_xor((int)s0, 32);
      unsigned int r1 = __shfl_xor((int)s1, 32);
      u32x4 f;
      f[0] = hh == 0 ? pk[base + 0] : r0;
      f[1] = hh == 0 ? pk[base + 1] : r1;
      f[2] = hh == 0 ? r0 : pk[base + 2];
      f[3] = hh == 0 ? r1 : pk[base + 3];
      pa[c] = *(bf16x8*)&f;
    }

    // O += P V : B=V frag from LDS: row d = dt*32+l31, k = c*16+hh*8
    __builtin_amdgcn_s_setprio(1);
    #pragma unroll
    for (int dt = 0; dt < 4; ++dt) {
      #pragma unroll
      for (int c = 0; c < 4; ++c) {
        int row = dt * 32 + l31;
        int byte = (row * 128 + c * 32 + hh * 16) ^ ((row & 7) << 4);
        bf16x8 vf = *(const bf16x8*)((const char*)Vls[cur] + byte);
        oacc[dt] = __builtin_amdgcn_mfma_f32_32x32x16_bf16(pa[c], vf, oacc[dt], 0, 0, 0);
      }
    }
    __builtin_amdgcn_s_setprio(0);

    asm volatile("s_waitcnt vmcnt(0)" ::: "memory");   // next tile landed
    __syncthreads();                                    // all waves done with buf cur
  }

  // epilogue: O[q][d] / l[q] -> Y (B,T,C).  lane holds d-col = dt*32+l31, 16 q-rows.
  float linv = 1.0f / lrun;
  #pragma unroll
  for (int r = 0; r < 16; ++r) {
    int qr = (r & 3) + 8 * (r >> 2) + 4 * hh;
    float li = __shfl(linv, qr);
    int qg = q0 + wv * 32 + qr;
    size_t base = ((size_t)b * T_SEQ + qg) * CC + h * HD;
    #pragma unroll
    for (int dt = 0; dt < 4; ++dt)
      Y[base + dt * 32 + l31] = f2bf(oacc[dt][r] * li);
  }
}

extern "C" void kernel_launch(void* const* d_in, const int* in_sizes, int n_in,
                              void* d_out, int out_size, void* d_ws, size_t ws_size,
                              hipStream_t stream) {
  const float* x     = (const float*)d_in[0];
  const float* Wqkv  = (const float*)d_in[1];
  const float* Wproj = (const float*)d_in[2];
  float* out = (float*)d_out;
  char* ws = (char*)d_ws;
  const size_t MB = 1024 * 1024;
  unsigned short* WqkvT  = (unsigned short*)(ws + 0);        // 24MB; dead after GEMM1
  unsigned short* vt     = (unsigned short*)(ws + 0);        // 16MB, aliases WqkvT
  unsigned short* WprojT = (unsigned short*)(ws + 24 * MB);  // 8MB
  unsigned short* xb     = (unsigned short*)(ws + 32 * MB);  // 16MB; dead after GEMM1
  unsigned short* y      = xb;                               // aliases xb
  unsigned short* q      = (unsigned short*)(ws + 48 * MB);  // 16MB
  unsigned short* k      = (unsigned short*)(ws + 64 * MB);  // 16MB
  unsigned short* v      = (unsigned short*)(ws + 80 * MB);  // 16MB  (total 96MB)

  k_transpose_cvt<<<dim3(CC / 32, N3 / 32), 256, 0, stream>>>(Wqkv, WqkvT, CC, N3);
  k_transpose_cvt<<<dim3(CC / 32, CC / 32), 256, 0, stream>>>(Wproj, WprojT, CC, CC);
  k_cvt<<<(MM * CC / 4) / 256, 256, 0, stream>>>(x, xb, MM * CC / 4);
  // GEMM1: 4096 x 6144 x 2048, BM=128 BN=384 -> grid 512 (exactly 2 gens), m-major chunks
  k_gemm8<6, 1, 1><<<dim3((MM / 128) * (N3 / 384)), 512, 131072, stream>>>(
      xb, WqkvT, nullptr, q, k, v, MM, N3, CC);
  k_rope<<<(32 * T_SEQ * 64) / 256, 256, 0, stream>>>(q, k);
  k_transpose_v<<<dim3(T_SEQ / 32, HD / 32, 32), 256, 0, stream>>>(v, vt);
  k_attn<<<dim3(512), 256, 0, stream>>>(q, k, vt, y);
  // GEMM2: 4096 x 2048 x 2048, BM=128 BN=256 -> grid 256 (exactly 1/CU), n-major chunks
  k_gemm8<4, 0, 0><<<dim3((MM / 128) * (CC / 256)), 512, 98304, stream>>>(
      y, WprojT, out, nullptr, nullptr, nullptr, MM, CC, CC);
}

// Round 11
// 266.673 us; speedup vs baseline: 1.6916x; 1.0168x over previous
//
#include <hip/hip_runtime.h>
#include <stdint.h>

#define T_SEQ 2048
#define NH 16
#define HD 128
#define CC 2048
#define N3 6144
#define MM 4096   // B*T

typedef short bf16x8 __attribute__((ext_vector_type(8)));
typedef float f32x4 __attribute__((ext_vector_type(4)));
typedef float f32x16 __attribute__((ext_vector_type(16)));
typedef unsigned int u32x4 __attribute__((ext_vector_type(4)));

__device__ __forceinline__ unsigned short f2bf(float f) {
  unsigned int u = __float_as_uint(f);
  u += 0x7FFF + ((u >> 16) & 1);   // RNE
  return (unsigned short)(u >> 16);
}
__device__ __forceinline__ float bf2f(unsigned short h) {
  return __uint_as_float(((unsigned int)h) << 16);
}
__device__ __forceinline__ unsigned int cvt_pk_bf16(float lo, float hi) {
  unsigned int r;
  asm("v_cvt_pk_bf16_f32 %0, %1, %2" : "=v"(r) : "v"(lo), "v"(hi));
  return r;
}

// ---------------- transpose + fp32->bf16 convert: out[n][k] = in[k][n] ----------------
__global__ __launch_bounds__(256) void k_transpose_cvt(const float* __restrict__ in,
                                                       unsigned short* __restrict__ out,
                                                       int K, int N) {
  __shared__ float tile[32][33];
  int k0 = blockIdx.x * 32;
  int n0 = blockIdx.y * 32;
  int tx = threadIdx.x & 31, ty = threadIdx.x >> 5;   // ty 0..7
  #pragma unroll
  for (int r = ty; r < 32; r += 8)
    tile[r][tx] = in[(size_t)(k0 + r) * N + n0 + tx];
  __syncthreads();
  #pragma unroll
  for (int r = ty; r < 32; r += 8)
    out[(size_t)(n0 + r) * K + k0 + tx] = f2bf(tile[tx][r]);
}

// ---------------- fp32 -> bf16 elementwise (x) ----------------
__global__ __launch_bounds__(256) void k_cvt(const float* __restrict__ in,
                                             unsigned short* __restrict__ out, int n4) {
  int i = blockIdx.x * 256 + threadIdx.x;
  if (i >= n4) return;
  float4 v = ((const float4*)in)[i];
  ushort4 o;
  o.x = f2bf(v.x); o.y = f2bf(v.y); o.z = f2bf(v.z); o.w = f2bf(v.w);
  ((ushort4*)out)[i] = o;
}

// ---------------- bf16 GEMM, merged 4-phase template, BM=128, BN=NJ*64 ------------------
// 512 threads = 8 waves (2M x 4N). BK=64, 2 K-tiles/iteration, 4 phases (24 or 16 MFMA ea).
// Swizzle: involutive XOR of byte bits[4:6] with row bits[0:2] (rows = 128B).
// Stage rotation (write-safety + landing both hand-verified, see analysis):
//   NJ=6: ph1: b.A->d1 | ph2: a'.B0,B1->d0, vmcnt(4) | ph3: a'.B2,a'.A->d0 | ph4: b'.B012->d1, vmcnt(6)
//   NJ=4: ph1: b.A->d1 | ph2: a'.B0->d0,   vmcnt(2) | ph3: a'.B1,a'.A->d0 | ph4: b'.B01->d1,  vmcnt(4)
// EPI==0: fp32 C.  EPI==1: scatter bf16 into q/k/v (B,H,T,D).  MMAJ: XCD-chunk axis.
template<int NJ, int EPI, int MMAJ>
__global__ __launch_bounds__(512, 1) void k_gemm8(const unsigned short* __restrict__ A,
                                                  const unsigned short* __restrict__ Bt,
                                                  float* __restrict__ C,
                                                  unsigned short* __restrict__ qo,
                                                  unsigned short* __restrict__ ko,
                                                  unsigned short* __restrict__ vo,
                                                  int M, int N, int K) {
  constexpr int BU = NJ / 2;             // B units of 128 rows
  constexpr int DSTRIDE = (1 + BU) * 16384;
  extern __shared__ __align__(16) char lds[];
  const int tid = threadIdx.x;
  const int lane = tid & 63;
  const int lr = lane & 15, lg = lane >> 4;
  const int wave = tid >> 6;
  const int wm = wave >> 2, wn = wave & 3;
  const int nwg = gridDim.x;
  const int bid = blockIdx.x;
  const int wg = (bid & 7) * (nwg >> 3) + (bid >> 3);
  const int GX = M >> 7;
  const int GN = N / (NJ * 64);
  const int mt = MMAJ ? (wg % GX) : (wg / GN);
  const int nt = MMAJ ? (wg / GX) : (wg % GN);
  const int m0 = mt * 128, n0 = nt * NJ * 64;
  const int NT = K >> 6;

  auto STAGE = [&](int d, int op, int h, int t) {
    const unsigned short* src = op ? Bt : A;
    const int r0 = (op ? n0 + h * 128 : m0);
    const int kc = t * 64;
    char* base = lds + d * DSTRIDE + op * 16384 + h * 16384;
    #pragma unroll
    for (int l = 0; l < 2; ++l) {
      int p = (l * 512 + tid) * 16;
      int qq = p ^ (((p >> 7) & 7) << 4);
      const unsigned short* g = src + (size_t)(r0 + (qq >> 7)) * K + kc + ((qq & 127) >> 1);
      __builtin_amdgcn_global_load_lds(
          (const __attribute__((address_space(1))) void*)g,
          (__attribute__((address_space(3))) void*)(base + (l * 512 + (tid & 448)) * 16),
          16, 0, 0);
    }
  };
  auto RD = [&](int d, int op, int row, int kb) -> bf16x8 {
    const char* base = lds + d * DSTRIDE + op * 16384;
    int p = row * 128 + kb;
    p ^= ((p >> 7) & 7) << 4;
    return *(const bf16x8*)(base + p);
  };

  f32x4 acc[4][NJ];
  #pragma unroll
  for (int i = 0; i < 4; ++i)
    #pragma unroll
    for (int j = 0; j < NJ; ++j) acc[i][j] = (f32x4){0.f, 0.f, 0.f, 0.f};

  bf16x8 bfrg[NJ][2];

// merged phase: 2 mi (MIB, MIB+1) x NJ x 2ks MFMA; stages passed as trailing statements
#define PHASE(D, MIB, READB, VM, ...)                                                    \
  {                                                                                      \
    if (READB) {                                                                         \
      _Pragma("unroll")                                                                  \
      for (int nj = 0; nj < NJ; ++nj)                                                    \
        _Pragma("unroll")                                                                \
        for (int ks = 0; ks < 2; ++ks)                                                   \
          bfrg[nj][ks] = RD(D, 1, wn * NJ * 16 + nj * 16 + lr, ks * 64 + lg * 16);       \
    }                                                                                    \
    bf16x8 af2[2][2];                                                                    \
    _Pragma("unroll")                                                                    \
    for (int mm = 0; mm < 2; ++mm)                                                       \
      _Pragma("unroll")                                                                  \
      for (int ks = 0; ks < 2; ++ks)                                                     \
        af2[mm][ks] = RD(D, 0, wm * 64 + (MIB + mm) * 16 + lr, ks * 64 + lg * 16);       \
    __VA_ARGS__                                                                          \
    __builtin_amdgcn_s_barrier();                                                        \
    asm volatile("s_waitcnt lgkmcnt(0)" ::: "memory");                                   \
    __builtin_amdgcn_s_setprio(1);                                                       \
    _Pragma("unroll")                                                                    \
    for (int mm = 0; mm < 2; ++mm)                                                       \
      _Pragma("unroll")                                                                  \
      for (int nj = 0; nj < NJ; ++nj)                                                    \
        _Pragma("unroll")                                                                \
        for (int ks = 0; ks < 2; ++ks)                                                   \
          acc[MIB + mm][nj] = __builtin_amdgcn_mfma_f32_16x16x32_bf16(af2[mm][ks], bfrg[nj][ks], acc[MIB + mm][nj], 0, 0, 0); \
    __builtin_amdgcn_s_setprio(0);                                                       \
    if ((VM) == 6) asm volatile("s_waitcnt vmcnt(6)" ::: "memory");                      \
    if ((VM) == 4) asm volatile("s_waitcnt vmcnt(4)" ::: "memory");                      \
    if ((VM) == 2) asm volatile("s_waitcnt vmcnt(2)" ::: "memory");                      \
    __builtin_amdgcn_s_barrier();                                                        \
  }

  // prologue: tile0 full -> d0 (B units then A), tile1 B units -> d1 (t1.A staged in ph1)
  const int t1 = NT > 1 ? 1 : 0;
  #pragma unroll
  for (int h = 0; h < BU; ++h) STAGE(0, 1, h, 0);
  STAGE(0, 0, 0, 0);
  #pragma unroll
  for (int h = 0; h < BU; ++h) STAGE(1, 1, h, t1);
  if (NJ == 6) asm volatile("s_waitcnt vmcnt(6)" ::: "memory");
  else         asm volatile("s_waitcnt vmcnt(4)" ::: "memory");
  __builtin_amdgcn_s_barrier();

  for (int it = 0; it < (NT >> 1); ++it) {
    const int tb  = 2 * it + 1;
    const int ta1 = min(2 * it + 2, NT - 1);
    const int tb1 = min(2 * it + 3, NT - 1);
    if (NJ == 6) {
      PHASE(0, 0, true,  -1, STAGE(1, 0, 0, tb);)
      PHASE(0, 2, false,  4, STAGE(0, 1, 0, ta1); STAGE(0, 1, 1, ta1);)
      PHASE(1, 0, true,  -1, STAGE(0, 1, 2, ta1); STAGE(0, 0, 0, ta1);)
      PHASE(1, 2, false,  6, STAGE(1, 1, 0, tb1); STAGE(1, 1, 1, tb1); STAGE(1, 1, 2, tb1);)
    } else {
      PHASE(0, 0, true,  -1, STAGE(1, 0, 0, tb);)
      PHASE(0, 2, false,  2, STAGE(0, 1, 0, ta1);)
      PHASE(1, 0, true,  -1, STAGE(0, 1, 1, ta1); STAGE(0, 0, 0, ta1);)
      PHASE(1, 2, false,  4, STAGE(1, 1, 0, tb1); STAGE(1, 1, 1, tb1);)
    }
  }
#undef PHASE

  #pragma unroll
  for (int mi = 0; mi < 4; ++mi) {
    #pragma unroll
    for (int nj = 0; nj < NJ; ++nj) {
      #pragma unroll
      for (int j = 0; j < 4; ++j) {
        int m = m0 + wm * 64 + mi * 16 + lg * 4 + j;
        int n = n0 + wn * NJ * 16 + nj * 16 + lr;
        float val = acc[mi][nj][j];
        if (EPI == 0) {
          C[(size_t)m * N + n] = val;
        } else {
          int which = n >> 11, cc = n & 2047;
          int h = cc >> 7, d = cc & 127;
          int b = m >> 11, t = m & 2047;
          unsigned short* dst = which == 0 ? qo : (which == 1 ? ko : vo);
          dst[(((size_t)(b * NH + h)) * T_SEQ + t) * HD + d] = f2bf(val);
        }
      }
    }
  }
}

// ---------------- RoPE in place on q (scaled by log2e/sqrt(D)) and k ----------------
__global__ __launch_bounds__(256) void k_rope(unsigned short* __restrict__ q,
                                              unsigned short* __restrict__ k) {
  int i = blockIdx.x * 256 + threadIdx.x;   // over 32 * 2048 * 64
  int d = i & 63;
  int t = (i >> 6) & (T_SEQ - 1);
  int bh = i >> 17;
  float invf = exp2f((float)(-2 * d) * (13.287712379549449f / 128.f)); // 10000^(-2d/128)
  float ang = (float)t * invf;
  float c = cosf(ang), s = sinf(ang);
  size_t base = ((size_t)bh * T_SEQ + t) * HD + d;
  const float scale = 0.12751741562076117f;  // log2(e)/sqrt(128): attn uses exp2
  float q1 = bf2f(q[base]), q2 = bf2f(q[base + 64]);
  q[base]      = f2bf((q1 * c - q2 * s) * scale);
  q[base + 64] = f2bf((q2 * c + q1 * s) * scale);
  float k1 = bf2f(k[base]), k2 = bf2f(k[base + 64]);
  k[base]      = f2bf(k1 * c - k2 * s);
  k[base + 64] = f2bf(k2 * c + k1 * s);
}

// ---------------- bf16 transpose per (b,h): (T,D) -> (D,T) ----------------
__global__ __launch_bounds__(256) void k_transpose_v(const unsigned short* __restrict__ in,
                                                     unsigned short* __restrict__ out) {
  __shared__ unsigned short tile[32][33];
  int bh = blockIdx.z;
  int t0 = blockIdx.x * 32, d0 = blockIdx.y * 32;
  int tx = threadIdx.x & 31, ty = threadIdx.x >> 5;
  const unsigned short* src = in + (size_t)bh * T_SEQ * HD;
  unsigned short* dst = out + (size_t)bh * HD * T_SEQ;
  #pragma unroll
  for (int r = ty; r < 32; r += 8)
    tile[r][tx] = src[(size_t)(t0 + r) * HD + d0 + tx];
  __syncthreads();
  #pragma unroll
  for (int r = ty; r < 32; r += 8)
    dst[(size_t)(d0 + r) * T_SEQ + t0 + tx] = tile[tx][r];
}

// ---------------- causal flash attention: swapped QK^T, 32x32 MFMA, in-register softmax --
// (round-10 structure, unchanged)
__global__ __launch_bounds__(256, 2) void k_attn(const unsigned short* __restrict__ Q,
                                                 const unsigned short* __restrict__ K,
                                                 const unsigned short* __restrict__ Vt,
                                                 unsigned short* __restrict__ Y) {
  __shared__ __align__(16) unsigned short Kls[2][64 * 128];   // [buf][k][d] swizzled
  __shared__ __align__(16) unsigned short Vls[2][128 * 64];   // [buf][d][k] swizzled
  const int id = blockIdx.x;            // 0..511
  const int sub = id & 255;
  const int bh = sub & 31;
  const int qtl = (id < 256) ? (15 - (sub >> 5)) : (sub >> 5);  // heavy first; pairs balance
  const int b = bh >> 4, h = bh & 15;
  const int tid = threadIdx.x, wv = tid >> 6, lane = tid & 63;
  const int l31 = lane & 31, hh = lane >> 5;
  const int q0 = qtl * 128;
  const int jtmax = 2 * qtl + 1;
  const int qglob = q0 + wv * 32 + l31;
  const unsigned short* Qb = Q + (size_t)bh * T_SEQ * HD;
  const unsigned short* Kb = K + (size_t)bh * T_SEQ * HD;
  const unsigned short* Vb = Vt + (size_t)bh * HD * T_SEQ;

  auto STAGEKV = [&](int tk, int bb) {
    #pragma unroll
    for (int ch = 0; ch < 4; ++ch) {
      int p = (ch * 256 + tid) * 16;
      int q = p ^ (((p >> 8) & 7) << 4);
      const unsigned short* g = Kb + (size_t)(tk + (q >> 8)) * HD + ((q & 255) >> 1);
      __builtin_amdgcn_global_load_lds(
          (const __attribute__((address_space(1))) void*)g,
          (__attribute__((address_space(3))) void*)((char*)Kls[bb] + (ch * 256 + (tid & 192)) * 16),
          16, 0, 0);
    }
    #pragma unroll
    for (int ch = 0; ch < 4; ++ch) {
      int p = (ch * 256 + tid) * 16;
      int q = p ^ (((p >> 7) & 7) << 4);
      const unsigned short* g = Vb + (size_t)(q >> 7) * T_SEQ + tk + ((q & 127) >> 1);
      __builtin_amdgcn_global_load_lds(
          (const __attribute__((address_space(1))) void*)g,
          (__attribute__((address_space(3))) void*)((char*)Vls[bb] + (ch * 256 + (tid & 192)) * 16),
          16, 0, 0);
    }
  };

  bf16x8 qfr[8];
  #pragma unroll
  for (int c = 0; c < 8; ++c)
    qfr[c] = *(const bf16x8*)(Qb + (size_t)qglob * HD + c * 16 + hh * 8);

  f32x16 oacc[4];
  #pragma unroll
  for (int dt = 0; dt < 4; ++dt)
    #pragma unroll
    for (int r = 0; r < 16; ++r) oacc[dt][r] = 0.f;
  float mrun = -1e30f, lrun = 0.f;

  STAGEKV(0, 0);
  asm volatile("s_waitcnt vmcnt(0)" ::: "memory");
  __syncthreads();

  for (int jt = 0; jt <= jtmax; ++jt) {
    const int cur = jt & 1;
    if (jt < jtmax) STAGEKV((jt + 1) * 64, cur ^ 1);

    f32x16 sacc[2];
    #pragma unroll
    for (int t = 0; t < 2; ++t)
      #pragma unroll
      for (int r = 0; r < 16; ++r) sacc[t][r] = 0.f;
    __builtin_amdgcn_s_setprio(1);
    #pragma unroll
    for (int s = 0; s < 8; ++s) {
      #pragma unroll
      for (int t = 0; t < 2; ++t) {
        int row = t * 32 + l31;
        int byte = (row * 256 + s * 32 + hh * 16) ^ ((row & 7) << 4);
        bf16x8 kf = *(const bf16x8*)((const char*)Kls[cur] + byte);
        sacc[t] = __builtin_amdgcn_mfma_f32_32x32x16_bf16(kf, qfr[s], sacc[t], 0, 0, 0);
      }
    }
    __builtin_amdgcn_s_setprio(0);

    if (jt >= 2 * qtl) {
      #pragma unroll
      for (int t = 0; t < 2; ++t)
        #pragma unroll
        for (int r = 0; r < 16; ++r) {
          int kg = jt * 64 + t * 32 + (r & 3) + 8 * (r >> 2) + 4 * hh;
          if (kg > qglob) sacc[t][r] = -1e30f;
        }
    }

    float pmax = sacc[0][0];
    #pragma unroll
    for (int r = 1; r < 16; ++r) pmax = fmaxf(pmax, sacc[0][r]);
    #pragma unroll
    for (int r = 0; r < 16; ++r) pmax = fmaxf(pmax, sacc[1][r]);
    pmax = fmaxf(pmax, __shfl_xor(pmax, 32));

    if (__any(pmax > mrun + 8.0f)) {
      float mnew = fmaxf(mrun, pmax);
      float osc = exp2f(mrun - mnew);
      lrun *= osc;
      mrun = mnew;
      #pragma unroll
      for (int r = 0; r < 16; ++r) {
        int qr = (r & 3) + 8 * (r >> 2) + 4 * hh;
        float sr = __shfl(osc, qr);
        #pragma unroll
        for (int dt = 0; dt < 4; ++dt) oacc[dt][r] *= sr;
      }
    }

    unsigned int pk[16];
    float rsum = 0.f;
    #pragma unroll
    for (int t = 0; t < 2; ++t)
      #pragma unroll
      for (int i = 0; i < 8; ++i) {
        float p0 = exp2f(sacc[t][2 * i] - mrun);
        float p1 = exp2f(sacc[t][2 * i + 1] - mrun);
        rsum += p0 + p1;
        pk[t * 8 + i] = cvt_pk_bf16(p0, p1);
      }
    rsum += __shfl_xor(rsum, 32);
    lrun += rsum;

    bf16x8 pa[4];
    #pragma unroll
    for (int c = 0; c < 4; ++c) {
      int base = (c >> 1) * 8 + (c & 1) * 4;
      unsigned int s0 = hh == 0 ? pk[base + 2] : pk[base + 0];
      unsigned int s1 = hh == 0 ? pk[base + 3] : pk[base + 1];
      unsigned int r0 = __shfl_xor((int)s0, 32);
      unsigned int r1 = __shfl_xor((int)s1, 32);
      u32x4 f;
      f[0] = hh == 0 ? pk[base + 0] : r0;
      f[1] = hh == 0 ? pk[base + 1] : r1;
      f[2] = hh == 0 ? r0 : pk[base + 2];
      f[3] = hh == 0 ? r1 : pk[base + 3];
      pa[c] = *(bf16x8*)&f;
    }

    __builtin_amdgcn_s_setprio(1);
    #pragma unroll
    for (int dt = 0; dt < 4; ++dt) {
      #pragma unroll
      for (int c = 0; c < 4; ++c) {
        int row = dt * 32 + l31;
        int byte = (row * 128 + c * 32 + hh * 16) ^ ((row & 7) << 4);
        bf16x8 vf = *(const bf16x8*)((const char*)Vls[cur] + byte);
        oacc[dt] = __builtin_amdgcn_mfma_f32_32x32x16_bf16(pa[c], vf, oacc[dt], 0, 0, 0);
      }
    }
    __builtin_amdgcn_s_setprio(0);

    asm volatile("s_waitcnt vmcnt(0)" ::: "memory");
    __syncthreads();
  }

  float linv = 1.0f / lrun;
  #pragma unroll
  for (int r = 0; r < 16; ++r) {
    int qr = (r & 3) + 8 * (r >> 2) + 4 * hh;
    float li = __shfl(linv, qr);
    int qg = q0 + wv * 32 + qr;
    size_t base = ((size_t)b * T_SEQ + qg) * CC + h * HD;
    #pragma unroll
    for (int dt = 0; dt < 4; ++dt)
      Y[base + dt * 32 + l31] = f2bf(oacc[dt][r] * li);
  }
}

extern "C" void kernel_launch(void* const* d_in, const int* in_sizes, int n_in,
                              void* d_out, int out_size, void* d_ws, size_t ws_size,
                              hipStream_t stream) {
  const float* x     = (const float*)d_in[0];
  const float* Wqkv  = (const float*)d_in[1];
  const float* Wproj = (const float*)d_in[2];
  float* out = (float*)d_out;
  char* ws = (char*)d_ws;
  const size_t MB = 1024 * 1024;
  unsigned short* WqkvT  = (unsigned short*)(ws + 0);        // 24MB; dead after GEMM1
  unsigned short* vt     = (unsigned short*)(ws + 0);        // 16MB, aliases WqkvT
  unsigned short* WprojT = (unsigned short*)(ws + 24 * MB);  // 8MB
  unsigned short* xb     = (unsigned short*)(ws + 32 * MB);  // 16MB; dead after GEMM1
  unsigned short* y      = xb;                               // aliases xb
  unsigned short* q      = (unsigned short*)(ws + 48 * MB);  // 16MB
  unsigned short* k      = (unsigned short*)(ws + 64 * MB);  // 16MB
  unsigned short* v      = (unsigned short*)(ws + 80 * MB);  // 16MB  (total 96MB)

  k_transpose_cvt<<<dim3(CC / 32, N3 / 32), 256, 0, stream>>>(Wqkv, WqkvT, CC, N3);
  k_transpose_cvt<<<dim3(CC / 32, CC / 32), 256, 0, stream>>>(Wproj, WprojT, CC, CC);
  k_cvt<<<(MM * CC / 4) / 256, 256, 0, stream>>>(x, xb, MM * CC / 4);
  // GEMM1: 4096 x 6144 x 2048, BM=128 BN=384 -> grid 512 (exactly 2 gens), m-major chunks
  k_gemm8<6, 1, 1><<<dim3((MM / 128) * (N3 / 384)), 512, 131072, stream>>>(
      xb, WqkvT, nullptr, q, k, v, MM, N3, CC);
  k_rope<<<(32 * T_SEQ * 64) / 256, 256, 0, stream>>>(q, k);
  k_transpose_v<<<dim3(T_SEQ / 32, HD / 32, 32), 256, 0, stream>>>(v, vt);
  k_attn<<<dim3(512), 256, 0, stream>>>(q, k, vt, y);
  // GEMM2: 4096 x 2048 x 2048, BM=128 BN=256 -> grid 256 (exactly 1/CU), n-major chunks
  k_gemm8<4, 0, 0><<<dim3((MM / 128) * (CC / 256)), 512, 98304, stream>>>(
      y, WprojT, out, nullptr, nullptr, nullptr, MM, CC, CC);
}